// Round 11
// baseline (295.831 us; speedup 1.0000x reference)
//
#include <hip/hip_runtime.h>

#define N_OBJ 1024
#define E_P   32768

typedef float f32x4 __attribute__((ext_vector_type(4)));
typedef short bf16x8 __attribute__((ext_vector_type(8)));
typedef unsigned short u16x4 __attribute__((ext_vector_type(4)));

__device__ __forceinline__ unsigned short f2bf(float f) {
    unsigned u = __float_as_uint(f);
    u = u + 0x7FFFu + ((u >> 16) & 1u);   // RNE
    return (unsigned short)(u >> 16);
}

// ================= k_copy: PURE streaming copy of bboxes (512 MB traffic) =================
__global__ __launch_bounds__(256) void k_copy(const float4* __restrict__ src,
                                              float4* __restrict__ dst) {
    int i = blockIdx.x * 256 + threadIdx.x;
    const int stride = 8192 * 256;
    #pragma unroll
    for (int it = 0; it < 8; ++it) {
        dst[i] = src[i];
        i += stride;
    }
}

// ================= k_a: weight transpose/convert + featsb + pairs/hist/rank (pure) =================
// grid 2112
__global__ __launch_bounds__(256) void k_a(const float* __restrict__ W1,
                                           const float* __restrict__ W2,
                                           const float* __restrict__ feats,
                                           const int* __restrict__ pairs,
                                           unsigned short* __restrict__ w1pqT,
                                           unsigned short* __restrict__ w1cT,
                                           unsigned short* __restrict__ w2T,
                                           unsigned short* __restrict__ featsb,
                                           float* __restrict__ out_pairs,
                                           int* __restrict__ counts,
                                           int* __restrict__ rank) {
    int job = blockIdx.x, tid = threadIdx.x;
    if (job >= 1856) {                 // pairs passthrough + histogram + rank
        int i = (job - 1856) * 256 + tid;
        out_pairs[i] = (float)pairs[i];
        if (i < E_P) rank[i] = atomicAdd(&counts[pairs[2 * i]], 1);
        return;
    }
    if (job >= 1600) {                 // featsb straight convert
        int base = (job - 1600) * 2048 + tid * 8;
        float4 v0 = *(const float4*)&feats[base];
        float4 v1 = *(const float4*)&feats[base + 4];
        u16x4 o0 = { f2bf(v0.x), f2bf(v0.y), f2bf(v0.z), f2bf(v0.w) };
        u16x4 o1 = { f2bf(v1.x), f2bf(v1.y), f2bf(v1.z), f2bf(v1.w) };
        *(u16x4*)&featsb[base] = o0;
        *(u16x4*)&featsb[base + 4] = o1;
        return;
    }
    const float* in; unsigned short* out;
    int LDI, LDO, r0, c0, nbase, kbase;
    if (job < 1024) {                  // W1[0:1024] -> w1pqT [2048][512]
        r0 = (job >> 5) * 32; c0 = (job & 31) * 32;
        in = W1; LDI = 1024; out = w1pqT; LDO = 512;
        nbase = c0 + (r0 >= 512 ? 1024 : 0); kbase = r0 & 511;
    } else if (job < 1088) {           // W1[1024:1088] -> w1cT [1024][64]
        int t = job - 1024; r0 = 1024 + (t >> 5) * 32; c0 = (t & 31) * 32;
        in = W1; LDI = 1024; out = w1cT; LDO = 64;
        nbase = c0; kbase = r0 - 1024;
    } else {                           // W2 [1024][512] -> w2T [512][1024]
        int t = job - 1088; r0 = (t >> 4) * 32; c0 = (t & 15) * 32;
        in = W2; LDI = 512; out = w2T; LDO = 1024;
        nbase = c0; kbase = r0;
    }
    __shared__ float lds[32][33];
    int ti = tid >> 3, tj = (tid & 7) * 4;
    float4 v = *(const float4*)&in[(size_t)(r0 + ti) * LDI + c0 + tj];
    lds[ti][tj] = v.x; lds[ti][tj + 1] = v.y; lds[ti][tj + 2] = v.z; lds[ti][tj + 3] = v.w;
    __syncthreads();
    int oc = tid >> 3, oj = (tid & 7) * 4;
    u16x4 o = { f2bf(lds[oj][oc]), f2bf(lds[oj + 1][oc]),
                f2bf(lds[oj + 2][oc]), f2bf(lds[oj + 3][oc]) };
    *(u16x4*)&out[(size_t)(nbase + oc) * LDO + kbase + oj] = o;
}

// ================= k_b: brec-build + scatter + PQ GEMM (pure) =================
// grid 641: role 0 = brec builder; 1..128 = scatter; 129..640 = GEMM
__global__ __launch_bounds__(256) void k_b(const int* __restrict__ counts,
                                           const int* __restrict__ rank,
                                           const int* __restrict__ pairs,
                                           int* __restrict__ csr_obj,
                                           unsigned* __restrict__ brec,
                                           int* __restrict__ bcnt,
                                           const unsigned short* __restrict__ featsb,
                                           const unsigned short* __restrict__ w1pqT,
                                           const float* __restrict__ b1,
                                           float* __restrict__ P, float* __restrict__ Q) {
    int role = blockIdx.x, tid = threadIdx.x;

    if (role >= 129) {                 // ---- PQ GEMM tile ----
        int job = role - 129;
        int m0 = (job >> 5) * 64, n0 = (job & 31) * 64;
        int w = tid >> 6, l = tid & 63;
        int ln = l & 15, kb = (l >> 4) * 8;
        int row = m0 + w * 16 + ln;
        f32x4 acc[4] = {};
        for (int k0 = 0; k0 < 512; k0 += 32) {
            bf16x8 a = *(const bf16x8*)&featsb[(size_t)row * 512 + k0 + kb];
            #pragma unroll
            for (int f = 0; f < 4; ++f) {
                bf16x8 b = *(const bf16x8*)&w1pqT[(size_t)(n0 + f * 16 + ln) * 512 + k0 + kb];
                acc[f] = __builtin_amdgcn_mfma_f32_16x16x32_bf16(a, b, acc[f], 0, 0, 0);
            }
        }
        int mr = m0 + w * 16 + (l >> 4) * 4;
        if (n0 < 1024) {
            #pragma unroll
            for (int f = 0; f < 4; ++f) {
                int n = n0 + f * 16 + ln;
                float b1v = b1[n];
                #pragma unroll
                for (int r = 0; r < 4; ++r)
                    P[(size_t)(mr + r) * 1024 + n] = acc[f][r] + b1v;
            }
        } else {
            #pragma unroll
            for (int f = 0; f < 4; ++f) {
                int n = n0 - 1024 + f * 16 + ln;
                #pragma unroll
                for (int r = 0; r < 4; ++r)
                    Q[(size_t)(mr + r) * 1024 + n] = acc[f][r];
            }
        }
        return;
    }

    // ---- roles 0..128: redundant exclusive scan of counts in LDS ----
    __shared__ int sbuf[2][256];
    __shared__ int soff[1024];
    int c[4]; int s = 0;
    #pragma unroll
    for (int i = 0; i < 4; ++i) { c[i] = counts[tid * 4 + i]; s += c[i]; }
    sbuf[0][tid] = s;
    __syncthreads();
    int sel = 0;
    for (int d = 1; d < 256; d <<= 1) {
        int v = sbuf[sel][tid];
        if (tid >= d) v += sbuf[sel][tid - d];
        sbuf[sel ^ 1][tid] = v;
        sel ^= 1;
        __syncthreads();
    }
    int base = sbuf[sel][tid] - s;
    int run = base;
    #pragma unroll
    for (int i = 0; i < 4; ++i) { soff[tid * 4 + i] = run; run += c[i]; }
    __syncthreads();

    if (role >= 1) {                   // ---- scatter (no atomics) ----
        int e = (role - 1) * 256 + tid;
        int sub = pairs[2 * e];
        csr_obj[soff[sub] + rank[e]] = pairs[2 * e + 1];
        return;
    }

    // ---- role 0: batch-32 records ----
    int nb[4]; int t = 0;
    #pragma unroll
    for (int i = 0; i < 4; ++i) { nb[i] = (c[i] + 31) >> 5; t += nb[i]; }
    __syncthreads();
    sbuf[0][tid] = t;
    __syncthreads();
    sel = 0;
    for (int d = 1; d < 256; d <<= 1) {
        int v = sbuf[sel][tid];
        if (tid >= d) v += sbuf[sel][tid - d];
        sbuf[sel ^ 1][tid] = v;
        sel ^= 1;
        __syncthreads();
    }
    int bpos = sbuf[sel][tid] - t;
    int run2 = base;
    #pragma unroll
    for (int i = 0; i < 4; ++i) {
        int seg = tid * 4 + i;
        for (int k = 0; k < nb[i]; ++k) {
            int st = run2 + k * 32;
            int cnt = c[i] - k * 32; if (cnt > 32) cnt = 32;
            brec[bpos++] = (unsigned)st | ((unsigned)seg << 16) | ((unsigned)(cnt - 1) << 26);
        }
        run2 += c[i];
    }
    if (tid == 255) bcnt[0] = bpos;
}

// ================= k_seg: DIAGNOSTIC 2x — each job done by two blocks, each adds h*0.5 =================
// grid 16384: job = bid>>1 -> batch b = job>>2, quarter qd = job&3
__global__ __launch_bounds__(256) void k_seg(const int* __restrict__ csr_obj,
                                             const unsigned* __restrict__ brec,
                                             const int* __restrict__ bcnt,
                                             const float* __restrict__ bb,
                                             const unsigned short* __restrict__ w1cT,
                                             const float* __restrict__ P,
                                             const float* __restrict__ Q,
                                             float* __restrict__ HS) {
    int job = blockIdx.x >> 1;
    int b = job >> 2, qd = job & 3;
    if (b >= bcnt[0]) return;
    unsigned rec = brec[b];
    const int start = rec & 0xFFFF;
    const int seg = (rec >> 16) & 0x3FF;
    const int n = ((rec >> 26) & 31) + 1;

    const int tid = threadIdx.x, w = tid >> 6, l = tid & 63;
    const int ln = l & 15, g4 = l >> 4, kb = g4 * 8;
    const int cbase = qd * 256;
    const int wbase = cbase + w * 64;

    __shared__ float qs[32][256];   // 32 KB

    {
        int p = tid >> 3, j = tid & 7;
        int op = csr_obj[start + (p < n ? p : n - 1)];
        const float* qrow = &Q[(size_t)op * 1024 + cbase];
        #pragma unroll
        for (int i = 0; i < 8; ++i) {
            int c = j * 4 + i * 32;
            *(float4*)&qs[p][c] = *(const float4*)&qrow[c];
        }
    }

    const int nA = n < 16 ? n : 16;
    const int nB = n - 16;
    int iA = start + (ln < nA ? ln : nA - 1);
    int iB = (nB > 0) ? (start + 16 + (ln < nB ? ln : nB - 1)) : iA;
    int objA = csr_obj[iA];
    int objB = csr_obj[iB];

    const float* brA = &bb[((size_t)seg * 1024 + (size_t)objA) * 64];
    const float* brB = &bb[((size_t)seg * 1024 + (size_t)objB) * 64];
    float4 a0 = *(const float4*)&brA[kb];
    float4 a1 = *(const float4*)&brA[kb + 4];
    float4 a2 = *(const float4*)&brA[32 + kb];
    float4 a3 = *(const float4*)&brA[32 + kb + 4];
    float4 c0 = *(const float4*)&brB[kb];
    float4 c1 = *(const float4*)&brB[kb + 4];
    float4 c2 = *(const float4*)&brB[32 + kb];
    float4 c3 = *(const float4*)&brB[32 + kb + 4];
    bf16x8 A0a, A1a, A0b, A1b;
    A0a[0] = (short)f2bf(a0.x); A0a[1] = (short)f2bf(a0.y); A0a[2] = (short)f2bf(a0.z); A0a[3] = (short)f2bf(a0.w);
    A0a[4] = (short)f2bf(a1.x); A0a[5] = (short)f2bf(a1.y); A0a[6] = (short)f2bf(a1.z); A0a[7] = (short)f2bf(a1.w);
    A1a[0] = (short)f2bf(a2.x); A1a[1] = (short)f2bf(a2.y); A1a[2] = (short)f2bf(a2.z); A1a[3] = (short)f2bf(a2.w);
    A1a[4] = (short)f2bf(a3.x); A1a[5] = (short)f2bf(a3.y); A1a[6] = (short)f2bf(a3.z); A1a[7] = (short)f2bf(a3.w);
    A0b[0] = (short)f2bf(c0.x); A0b[1] = (short)f2bf(c0.y); A0b[2] = (short)f2bf(c0.z); A0b[3] = (short)f2bf(c0.w);
    A0b[4] = (short)f2bf(c1.x); A0b[5] = (short)f2bf(c1.y); A0b[6] = (short)f2bf(c1.z); A0b[7] = (short)f2bf(c1.w);
    A1b[0] = (short)f2bf(c2.x); A1b[1] = (short)f2bf(c2.y); A1b[2] = (short)f2bf(c2.z); A1b[3] = (short)f2bf(c2.w);
    A1b[4] = (short)f2bf(c3.x); A1b[5] = (short)f2bf(c3.y); A1b[6] = (short)f2bf(c3.z); A1b[7] = (short)f2bf(c3.w);

    bool vA0 = (g4 * 4 + 0) < nA, vA1 = (g4 * 4 + 1) < nA;
    bool vA2 = (g4 * 4 + 2) < nA, vA3 = (g4 * 4 + 3) < nA;
    bool vB0 = (g4 * 4 + 0) < nB, vB1 = (g4 * 4 + 1) < nB;
    bool vB2 = (g4 * 4 + 2) < nB, vB3 = (g4 * 4 + 3) < nB;

    float pv[4];
    #pragma unroll
    for (int f = 0; f < 4; ++f)
        pv[f] = P[(size_t)seg * 1024 + wbase + f * 16 + ln];

    __syncthreads();

    #pragma unroll
    for (int f = 0; f < 4; ++f) {
        int col = wbase + f * 16 + ln;
        int cc = col - cbase;
        const unsigned short* wr = &w1cT[(size_t)col * 64];
        bf16x8 b0 = *(const bf16x8*)&wr[kb];
        bf16x8 b1 = *(const bf16x8*)&wr[32 + kb];
        f32x4 dA = {0.f, 0.f, 0.f, 0.f};
        dA = __builtin_amdgcn_mfma_f32_16x16x32_bf16(A0a, b0, dA, 0, 0, 0);
        dA = __builtin_amdgcn_mfma_f32_16x16x32_bf16(A1a, b1, dA, 0, 0, 0);
        f32x4 dB = {0.f, 0.f, 0.f, 0.f};
        dB = __builtin_amdgcn_mfma_f32_16x16x32_bf16(A0b, b0, dB, 0, 0, 0);
        dB = __builtin_amdgcn_mfma_f32_16x16x32_bf16(A1b, b1, dB, 0, 0, 0);
        float qA0 = qs[g4 * 4 + 0][cc];
        float qA1 = qs[g4 * 4 + 1][cc];
        float qA2 = qs[g4 * 4 + 2][cc];
        float qA3 = qs[g4 * 4 + 3][cc];
        float qB0 = qs[16 + g4 * 4 + 0][cc];
        float qB1 = qs[16 + g4 * 4 + 1][cc];
        float qB2 = qs[16 + g4 * 4 + 2][cc];
        float qB3 = qs[16 + g4 * 4 + 3][cc];
        float h = 0.f;
        h += vA0 ? fmaxf(dA[0] + pv[f] + qA0, 0.f) : 0.f;
        h += vA1 ? fmaxf(dA[1] + pv[f] + qA1, 0.f) : 0.f;
        h += vA2 ? fmaxf(dA[2] + pv[f] + qA2, 0.f) : 0.f;
        h += vA3 ? fmaxf(dA[3] + pv[f] + qA3, 0.f) : 0.f;
        h += vB0 ? fmaxf(dB[0] + pv[f] + qB0, 0.f) : 0.f;
        h += vB1 ? fmaxf(dB[1] + pv[f] + qB1, 0.f) : 0.f;
        h += vB2 ? fmaxf(dB[2] + pv[f] + qB2, 0.f) : 0.f;
        h += vB3 ? fmaxf(dB[3] + pv[f] + qB3, 0.f) : 0.f;
        h += __shfl_xor(h, 16);
        h += __shfl_xor(h, 32);
        if (l < 16) atomicAdd(&HS[(size_t)seg * 1024 + wbase + f * 16 + l], h * 0.5f);
    }
}

// ================= k_out: (feats + HS@W2 + cnt*b2)/(1+cnt) (pure) =================
// grid 128
__global__ __launch_bounds__(256) void k_out(const float* __restrict__ HS,
                                             const unsigned short* __restrict__ w2T,
                                             const float* __restrict__ feats,
                                             const float* __restrict__ b2,
                                             const int* __restrict__ counts,
                                             float* __restrict__ out0) {
    int job = blockIdx.x;
    int m0 = (job >> 3) * 64, n0 = (job & 7) * 64;
    int tid = threadIdx.x, w = tid >> 6, l = tid & 63;
    int ln = l & 15, kb = (l >> 4) * 8;
    int row = m0 + w * 16 + ln;
    f32x4 acc[4] = {};
    for (int k0 = 0; k0 < 1024; k0 += 32) {
        const float* hp = &HS[(size_t)row * 1024 + k0 + kb];
        float4 h0 = *(const float4*)&hp[0];
        float4 h1 = *(const float4*)&hp[4];
        bf16x8 a;
        a[0] = (short)f2bf(h0.x); a[1] = (short)f2bf(h0.y); a[2] = (short)f2bf(h0.z); a[3] = (short)f2bf(h0.w);
        a[4] = (short)f2bf(h1.x); a[5] = (short)f2bf(h1.y); a[6] = (short)f2bf(h1.z); a[7] = (short)f2bf(h1.w);
        #pragma unroll
        for (int f = 0; f < 4; ++f) {
            bf16x8 b = *(const bf16x8*)&w2T[(size_t)(n0 + f * 16 + ln) * 1024 + k0 + kb];
            acc[f] = __builtin_amdgcn_mfma_f32_16x16x32_bf16(a, b, acc[f], 0, 0, 0);
        }
    }
    int mr = m0 + w * 16 + (l >> 4) * 4;
    float cv[4], inv[4];
    #pragma unroll
    for (int r = 0; r < 4; ++r) {
        float c = (float)counts[mr + r];
        cv[r] = c;
        inv[r] = 1.0f / (1.0f + c);
    }
    #pragma unroll
    for (int f = 0; f < 4; ++f) {
        int n = n0 + f * 16 + ln;
        float b2v = b2[n];
        #pragma unroll
        for (int r = 0; r < 4; ++r) {
            float fv = feats[(size_t)(mr + r) * 512 + n];
            out0[(size_t)(mr + r) * 512 + n] = (fv + acc[f][r] + cv[r] * b2v) * inv[r];
        }
    }
}

extern "C" void kernel_launch(void* const* d_in, const int* in_sizes, int n_in,
                              void* d_out, int out_size, void* d_ws, size_t ws_size,
                              hipStream_t stream) {
    const float* feats = (const float*)d_in[0];
    const float* bb    = (const float*)d_in[1];
    const int*   pairs = (const int*)d_in[2];
    const float* W1    = (const float*)d_in[3];
    const float* b1    = (const float*)d_in[4];
    const float* W2    = (const float*)d_in[5];
    const float* b2    = (const float*)d_in[6];

    float* out        = (float*)d_out;
    float* out_feats  = out;
    float* out_bb     = out + (size_t)N_OBJ * 512;
    float* out_pairs  = out + (size_t)N_OBJ * 512 + (size_t)N_OBJ * N_OBJ * 64;

    char* w = (char*)d_ws;
    unsigned short* featsb = (unsigned short*)w;
    unsigned short* w1pqT  = (unsigned short*)(w + (1u << 20));
    float*          HS     = (float*)w;
    unsigned short* w1cT   = (unsigned short*)(w + (4u << 20));
    unsigned short* w2T    = (unsigned short*)(w + (4u << 20) + (128u << 10));
    float* P = (float*)(w + (5u << 20) + (128u << 10));
    float* Q = (float*)(w + (9u << 20) + (128u << 10));
    char* ints = w + (13u << 20) + (128u << 10);
    int*      counts  = (int*)ints;
    int*      csr_obj = (int*)(ints + 4096);
    unsigned* brec    = (unsigned*)(ints + 4096 + 131072);
    int*      bcnt    = (int*)(ints + 4096 + 131072 + 16384);
    int*      rank    = (int*)(ints + 4096 + 131072 + 16384 + 64);

    hipMemsetAsync(counts, 0, 4096, stream);

    k_a<<<2112, 256, 0, stream>>>(W1, W2, feats, pairs, w1pqT, w1cT, w2T, featsb,
                                  out_pairs, counts, rank);
    k_b<<<641, 256, 0, stream>>>(counts, rank, pairs, csr_obj, brec, bcnt,
                                 featsb, w1pqT, b1, P, Q);

    hipMemsetAsync(HS, 0, (size_t)N_OBJ * 1024 * sizeof(float), stream);

    k_seg<<<16384, 256, 0, stream>>>(csr_obj, brec, bcnt, bb, w1cT, P, Q, HS);
    k_out<<<128, 256, 0, stream>>>(HS, w2T, feats, b2, counts, out_feats);

    k_copy<<<8192, 256, 0, stream>>>((const float4*)bb, (float4*)out_bb);
}

// Round 12
// 248.684 us; speedup vs baseline: 1.1896x; 1.1896x over previous
//
#include <hip/hip_runtime.h>

#define N_OBJ 1024
#define E_P   32768

typedef float f32x4 __attribute__((ext_vector_type(4)));
typedef short bf16x8 __attribute__((ext_vector_type(8)));
typedef unsigned short u16x4 __attribute__((ext_vector_type(4)));

__device__ __forceinline__ unsigned short f2bf(float f) {
    unsigned u = __float_as_uint(f);
    u = u + 0x7FFFu + ((u >> 16) & 1u);   // RNE
    return (unsigned short)(u >> 16);
}

// ================= k_zero: zero counts (4 KB) — replaces pathological hipMemsetAsync =================
__global__ __launch_bounds__(256) void k_zero(int* __restrict__ counts) {
    ((int4*)counts)[threadIdx.x] = make_int4(0, 0, 0, 0);   // 256 * 16B = 4 KB
}

// ================= k_zero_hs: zero HS (4 MB) — replaces pathological hipMemsetAsync =================
__global__ __launch_bounds__(256) void k_zero_hs(float4* __restrict__ hs4) {
    int i = blockIdx.x * 256 + threadIdx.x;
    const int stride = 256 * 256;
    float4 z = make_float4(0.f, 0.f, 0.f, 0.f);
    #pragma unroll
    for (int it = 0; it < 4; ++it) { hs4[i] = z; i += stride; }  // 262144 float4
}

// ================= k_copy: PURE streaming copy of bboxes (512 MB traffic) =================
__global__ __launch_bounds__(256) void k_copy(const float4* __restrict__ src,
                                              float4* __restrict__ dst) {
    int i = blockIdx.x * 256 + threadIdx.x;
    const int stride = 8192 * 256;
    #pragma unroll
    for (int it = 0; it < 8; ++it) {
        dst[i] = src[i];
        i += stride;
    }
}

// ================= k_a: weight transpose/convert + featsb + pairs/hist/rank (pure) =================
// grid 2112
__global__ __launch_bounds__(256) void k_a(const float* __restrict__ W1,
                                           const float* __restrict__ W2,
                                           const float* __restrict__ feats,
                                           const int* __restrict__ pairs,
                                           unsigned short* __restrict__ w1pqT,
                                           unsigned short* __restrict__ w1cT,
                                           unsigned short* __restrict__ w2T,
                                           unsigned short* __restrict__ featsb,
                                           float* __restrict__ out_pairs,
                                           int* __restrict__ counts,
                                           int* __restrict__ rank) {
    int job = blockIdx.x, tid = threadIdx.x;
    if (job >= 1856) {                 // pairs passthrough + histogram + rank
        int i = (job - 1856) * 256 + tid;
        out_pairs[i] = (float)pairs[i];
        if (i < E_P) rank[i] = atomicAdd(&counts[pairs[2 * i]], 1);
        return;
    }
    if (job >= 1600) {                 // featsb straight convert
        int base = (job - 1600) * 2048 + tid * 8;
        float4 v0 = *(const float4*)&feats[base];
        float4 v1 = *(const float4*)&feats[base + 4];
        u16x4 o0 = { f2bf(v0.x), f2bf(v0.y), f2bf(v0.z), f2bf(v0.w) };
        u16x4 o1 = { f2bf(v1.x), f2bf(v1.y), f2bf(v1.z), f2bf(v1.w) };
        *(u16x4*)&featsb[base] = o0;
        *(u16x4*)&featsb[base + 4] = o1;
        return;
    }
    const float* in; unsigned short* out;
    int LDI, LDO, r0, c0, nbase, kbase;
    if (job < 1024) {                  // W1[0:1024] -> w1pqT [2048][512]
        r0 = (job >> 5) * 32; c0 = (job & 31) * 32;
        in = W1; LDI = 1024; out = w1pqT; LDO = 512;
        nbase = c0 + (r0 >= 512 ? 1024 : 0); kbase = r0 & 511;
    } else if (job < 1088) {           // W1[1024:1088] -> w1cT [1024][64]
        int t = job - 1024; r0 = 1024 + (t >> 5) * 32; c0 = (t & 31) * 32;
        in = W1; LDI = 1024; out = w1cT; LDO = 64;
        nbase = c0; kbase = r0 - 1024;
    } else {                           // W2 [1024][512] -> w2T [512][1024]
        int t = job - 1088; r0 = (t >> 4) * 32; c0 = (t & 15) * 32;
        in = W2; LDI = 512; out = w2T; LDO = 1024;
        nbase = c0; kbase = r0;
    }
    __shared__ float lds[32][33];
    int ti = tid >> 3, tj = (tid & 7) * 4;
    float4 v = *(const float4*)&in[(size_t)(r0 + ti) * LDI + c0 + tj];
    lds[ti][tj] = v.x; lds[ti][tj + 1] = v.y; lds[ti][tj + 2] = v.z; lds[ti][tj + 3] = v.w;
    __syncthreads();
    int oc = tid >> 3, oj = (tid & 7) * 4;
    u16x4 o = { f2bf(lds[oj][oc]), f2bf(lds[oj + 1][oc]),
                f2bf(lds[oj + 2][oc]), f2bf(lds[oj + 3][oc]) };
    *(u16x4*)&out[(size_t)(nbase + oc) * LDO + kbase + oj] = o;
}

// ================= k_b: brec-build + scatter + PQ GEMM (pure) =================
// grid 641: role 0 = brec builder; 1..128 = scatter; 129..640 = GEMM
__global__ __launch_bounds__(256) void k_b(const int* __restrict__ counts,
                                           const int* __restrict__ rank,
                                           const int* __restrict__ pairs,
                                           int* __restrict__ csr_obj,
                                           unsigned* __restrict__ brec,
                                           int* __restrict__ bcnt,
                                           const unsigned short* __restrict__ featsb,
                                           const unsigned short* __restrict__ w1pqT,
                                           const float* __restrict__ b1,
                                           float* __restrict__ P, float* __restrict__ Q) {
    int role = blockIdx.x, tid = threadIdx.x;

    if (role >= 129) {                 // ---- PQ GEMM tile ----
        int job = role - 129;
        int m0 = (job >> 5) * 64, n0 = (job & 31) * 64;
        int w = tid >> 6, l = tid & 63;
        int ln = l & 15, kb = (l >> 4) * 8;
        int row = m0 + w * 16 + ln;
        f32x4 acc[4] = {};
        for (int k0 = 0; k0 < 512; k0 += 32) {
            bf16x8 a = *(const bf16x8*)&featsb[(size_t)row * 512 + k0 + kb];
            #pragma unroll
            for (int f = 0; f < 4; ++f) {
                bf16x8 b = *(const bf16x8*)&w1pqT[(size_t)(n0 + f * 16 + ln) * 512 + k0 + kb];
                acc[f] = __builtin_amdgcn_mfma_f32_16x16x32_bf16(a, b, acc[f], 0, 0, 0);
            }
        }
        int mr = m0 + w * 16 + (l >> 4) * 4;
        if (n0 < 1024) {
            #pragma unroll
            for (int f = 0; f < 4; ++f) {
                int n = n0 + f * 16 + ln;
                float b1v = b1[n];
                #pragma unroll
                for (int r = 0; r < 4; ++r)
                    P[(size_t)(mr + r) * 1024 + n] = acc[f][r] + b1v;
            }
        } else {
            #pragma unroll
            for (int f = 0; f < 4; ++f) {
                int n = n0 - 1024 + f * 16 + ln;
                #pragma unroll
                for (int r = 0; r < 4; ++r)
                    Q[(size_t)(mr + r) * 1024 + n] = acc[f][r];
            }
        }
        return;
    }

    // ---- roles 0..128: redundant exclusive scan of counts in LDS ----
    __shared__ int sbuf[2][256];
    __shared__ int soff[1024];
    int c[4]; int s = 0;
    #pragma unroll
    for (int i = 0; i < 4; ++i) { c[i] = counts[tid * 4 + i]; s += c[i]; }
    sbuf[0][tid] = s;
    __syncthreads();
    int sel = 0;
    for (int d = 1; d < 256; d <<= 1) {
        int v = sbuf[sel][tid];
        if (tid >= d) v += sbuf[sel][tid - d];
        sbuf[sel ^ 1][tid] = v;
        sel ^= 1;
        __syncthreads();
    }
    int base = sbuf[sel][tid] - s;
    int run = base;
    #pragma unroll
    for (int i = 0; i < 4; ++i) { soff[tid * 4 + i] = run; run += c[i]; }
    __syncthreads();

    if (role >= 1) {                   // ---- scatter (no atomics) ----
        int e = (role - 1) * 256 + tid;
        int sub = pairs[2 * e];
        csr_obj[soff[sub] + rank[e]] = pairs[2 * e + 1];
        return;
    }

    // ---- role 0: batch-32 records ----
    int nb[4]; int t = 0;
    #pragma unroll
    for (int i = 0; i < 4; ++i) { nb[i] = (c[i] + 31) >> 5; t += nb[i]; }
    __syncthreads();
    sbuf[0][tid] = t;
    __syncthreads();
    sel = 0;
    for (int d = 1; d < 256; d <<= 1) {
        int v = sbuf[sel][tid];
        if (tid >= d) v += sbuf[sel][tid - d];
        sbuf[sel ^ 1][tid] = v;
        sel ^= 1;
        __syncthreads();
    }
    int bpos = sbuf[sel][tid] - t;
    int run2 = base;
    #pragma unroll
    for (int i = 0; i < 4; ++i) {
        int seg = tid * 4 + i;
        for (int k = 0; k < nb[i]; ++k) {
            int st = run2 + k * 32;
            int cnt = c[i] - k * 32; if (cnt > 32) cnt = 32;
            brec[bpos++] = (unsigned)st | ((unsigned)seg << 16) | ((unsigned)(cnt - 1) << 26);
        }
        run2 += c[i];
    }
    if (tid == 255) bcnt[0] = bpos;
}

// ================= k_seg: quarter-blocks + LDS-staged Q (pure) =================
// grid 8192: job = bid -> batch b = job>>2, column-quarter qd = job&3 (256 cols)
__global__ __launch_bounds__(256) void k_seg(const int* __restrict__ csr_obj,
                                             const unsigned* __restrict__ brec,
                                             const int* __restrict__ bcnt,
                                             const float* __restrict__ bb,
                                             const unsigned short* __restrict__ w1cT,
                                             const float* __restrict__ P,
                                             const float* __restrict__ Q,
                                             float* __restrict__ HS) {
    int job = blockIdx.x;
    int b = job >> 2, qd = job & 3;
    if (b >= bcnt[0]) return;
    unsigned rec = brec[b];
    const int start = rec & 0xFFFF;
    const int seg = (rec >> 16) & 0x3FF;
    const int n = ((rec >> 26) & 31) + 1;

    const int tid = threadIdx.x, w = tid >> 6, l = tid & 63;
    const int ln = l & 15, g4 = l >> 4, kb = g4 * 8;
    const int cbase = qd * 256;
    const int wbase = cbase + w * 64;

    __shared__ float qs[32][256];   // 32 KB

    {
        int p = tid >> 3, j = tid & 7;
        int op = csr_obj[start + (p < n ? p : n - 1)];
        const float* qrow = &Q[(size_t)op * 1024 + cbase];
        #pragma unroll
        for (int i = 0; i < 8; ++i) {
            int c = j * 4 + i * 32;
            *(float4*)&qs[p][c] = *(const float4*)&qrow[c];
        }
    }

    const int nA = n < 16 ? n : 16;
    const int nB = n - 16;
    int iA = start + (ln < nA ? ln : nA - 1);
    int iB = (nB > 0) ? (start + 16 + (ln < nB ? ln : nB - 1)) : iA;
    int objA = csr_obj[iA];
    int objB = csr_obj[iB];

    const float* brA = &bb[((size_t)seg * 1024 + (size_t)objA) * 64];
    const float* brB = &bb[((size_t)seg * 1024 + (size_t)objB) * 64];
    float4 a0 = *(const float4*)&brA[kb];
    float4 a1 = *(const float4*)&brA[kb + 4];
    float4 a2 = *(const float4*)&brA[32 + kb];
    float4 a3 = *(const float4*)&brA[32 + kb + 4];
    float4 c0 = *(const float4*)&brB[kb];
    float4 c1 = *(const float4*)&brB[kb + 4];
    float4 c2 = *(const float4*)&brB[32 + kb];
    float4 c3 = *(const float4*)&brB[32 + kb + 4];
    bf16x8 A0a, A1a, A0b, A1b;
    A0a[0] = (short)f2bf(a0.x); A0a[1] = (short)f2bf(a0.y); A0a[2] = (short)f2bf(a0.z); A0a[3] = (short)f2bf(a0.w);
    A0a[4] = (short)f2bf(a1.x); A0a[5] = (short)f2bf(a1.y); A0a[6] = (short)f2bf(a1.z); A0a[7] = (short)f2bf(a1.w);
    A1a[0] = (short)f2bf(a2.x); A1a[1] = (short)f2bf(a2.y); A1a[2] = (short)f2bf(a2.z); A1a[3] = (short)f2bf(a2.w);
    A1a[4] = (short)f2bf(a3.x); A1a[5] = (short)f2bf(a3.y); A1a[6] = (short)f2bf(a3.z); A1a[7] = (short)f2bf(a3.w);
    A0b[0] = (short)f2bf(c0.x); A0b[1] = (short)f2bf(c0.y); A0b[2] = (short)f2bf(c0.z); A0b[3] = (short)f2bf(c0.w);
    A0b[4] = (short)f2bf(c1.x); A0b[5] = (short)f2bf(c1.y); A0b[6] = (short)f2bf(c1.z); A0b[7] = (short)f2bf(c1.w);
    A1b[0] = (short)f2bf(c2.x); A1b[1] = (short)f2bf(c2.y); A1b[2] = (short)f2bf(c2.z); A1b[3] = (short)f2bf(c2.w);
    A1b[4] = (short)f2bf(c3.x); A1b[5] = (short)f2bf(c3.y); A1b[6] = (short)f2bf(c3.z); A1b[7] = (short)f2bf(c3.w);

    bool vA0 = (g4 * 4 + 0) < nA, vA1 = (g4 * 4 + 1) < nA;
    bool vA2 = (g4 * 4 + 2) < nA, vA3 = (g4 * 4 + 3) < nA;
    bool vB0 = (g4 * 4 + 0) < nB, vB1 = (g4 * 4 + 1) < nB;
    bool vB2 = (g4 * 4 + 2) < nB, vB3 = (g4 * 4 + 3) < nB;

    float pv[4];
    #pragma unroll
    for (int f = 0; f < 4; ++f)
        pv[f] = P[(size_t)seg * 1024 + wbase + f * 16 + ln];

    __syncthreads();

    #pragma unroll
    for (int f = 0; f < 4; ++f) {
        int col = wbase + f * 16 + ln;
        int cc = col - cbase;
        const unsigned short* wr = &w1cT[(size_t)col * 64];
        bf16x8 b0 = *(const bf16x8*)&wr[kb];
        bf16x8 b1 = *(const bf16x8*)&wr[32 + kb];
        f32x4 dA = {0.f, 0.f, 0.f, 0.f};
        dA = __builtin_amdgcn_mfma_f32_16x16x32_bf16(A0a, b0, dA, 0, 0, 0);
        dA = __builtin_amdgcn_mfma_f32_16x16x32_bf16(A1a, b1, dA, 0, 0, 0);
        f32x4 dB = {0.f, 0.f, 0.f, 0.f};
        dB = __builtin_amdgcn_mfma_f32_16x16x32_bf16(A0b, b0, dB, 0, 0, 0);
        dB = __builtin_amdgcn_mfma_f32_16x16x32_bf16(A1b, b1, dB, 0, 0, 0);
        float qA0 = qs[g4 * 4 + 0][cc];
        float qA1 = qs[g4 * 4 + 1][cc];
        float qA2 = qs[g4 * 4 + 2][cc];
        float qA3 = qs[g4 * 4 + 3][cc];
        float qB0 = qs[16 + g4 * 4 + 0][cc];
        float qB1 = qs[16 + g4 * 4 + 1][cc];
        float qB2 = qs[16 + g4 * 4 + 2][cc];
        float qB3 = qs[16 + g4 * 4 + 3][cc];
        float h = 0.f;
        h += vA0 ? fmaxf(dA[0] + pv[f] + qA0, 0.f) : 0.f;
        h += vA1 ? fmaxf(dA[1] + pv[f] + qA1, 0.f) : 0.f;
        h += vA2 ? fmaxf(dA[2] + pv[f] + qA2, 0.f) : 0.f;
        h += vA3 ? fmaxf(dA[3] + pv[f] + qA3, 0.f) : 0.f;
        h += vB0 ? fmaxf(dB[0] + pv[f] + qB0, 0.f) : 0.f;
        h += vB1 ? fmaxf(dB[1] + pv[f] + qB1, 0.f) : 0.f;
        h += vB2 ? fmaxf(dB[2] + pv[f] + qB2, 0.f) : 0.f;
        h += vB3 ? fmaxf(dB[3] + pv[f] + qB3, 0.f) : 0.f;
        h += __shfl_xor(h, 16);
        h += __shfl_xor(h, 32);
        if (l < 16) atomicAdd(&HS[(size_t)seg * 1024 + wbase + f * 16 + l], h);
    }
}

// ================= k_out: (feats + HS@W2 + cnt*b2)/(1+cnt) (pure) =================
// grid 128
__global__ __launch_bounds__(256) void k_out(const float* __restrict__ HS,
                                             const unsigned short* __restrict__ w2T,
                                             const float* __restrict__ feats,
                                             const float* __restrict__ b2,
                                             const int* __restrict__ counts,
                                             float* __restrict__ out0) {
    int job = blockIdx.x;
    int m0 = (job >> 3) * 64, n0 = (job & 7) * 64;
    int tid = threadIdx.x, w = tid >> 6, l = tid & 63;
    int ln = l & 15, kb = (l >> 4) * 8;
    int row = m0 + w * 16 + ln;
    f32x4 acc[4] = {};
    for (int k0 = 0; k0 < 1024; k0 += 32) {
        const float* hp = &HS[(size_t)row * 1024 + k0 + kb];
        float4 h0 = *(const float4*)&hp[0];
        float4 h1 = *(const float4*)&hp[4];
        bf16x8 a;
        a[0] = (short)f2bf(h0.x); a[1] = (short)f2bf(h0.y); a[2] = (short)f2bf(h0.z); a[3] = (short)f2bf(h0.w);
        a[4] = (short)f2bf(h1.x); a[5] = (short)f2bf(h1.y); a[6] = (short)f2bf(h1.z); a[7] = (short)f2bf(h1.w);
        #pragma unroll
        for (int f = 0; f < 4; ++f) {
            bf16x8 b = *(const bf16x8*)&w2T[(size_t)(n0 + f * 16 + ln) * 1024 + k0 + kb];
            acc[f] = __builtin_amdgcn_mfma_f32_16x16x32_bf16(a, b, acc[f], 0, 0, 0);
        }
    }
    int mr = m0 + w * 16 + (l >> 4) * 4;
    float cv[4], inv[4];
    #pragma unroll
    for (int r = 0; r < 4; ++r) {
        float c = (float)counts[mr + r];
        cv[r] = c;
        inv[r] = 1.0f / (1.0f + c);
    }
    #pragma unroll
    for (int f = 0; f < 4; ++f) {
        int n = n0 + f * 16 + ln;
        float b2v = b2[n];
        #pragma unroll
        for (int r = 0; r < 4; ++r) {
            float fv = feats[(size_t)(mr + r) * 512 + n];
            out0[(size_t)(mr + r) * 512 + n] = (fv + acc[f][r] + cv[r] * b2v) * inv[r];
        }
    }
}

extern "C" void kernel_launch(void* const* d_in, const int* in_sizes, int n_in,
                              void* d_out, int out_size, void* d_ws, size_t ws_size,
                              hipStream_t stream) {
    const float* feats = (const float*)d_in[0];
    const float* bb    = (const float*)d_in[1];
    const int*   pairs = (const int*)d_in[2];
    const float* W1    = (const float*)d_in[3];
    const float* b1    = (const float*)d_in[4];
    const float* W2    = (const float*)d_in[5];
    const float* b2    = (const float*)d_in[6];

    float* out        = (float*)d_out;
    float* out_feats  = out;
    float* out_bb     = out + (size_t)N_OBJ * 512;
    float* out_pairs  = out + (size_t)N_OBJ * 512 + (size_t)N_OBJ * N_OBJ * 64;

    char* w = (char*)d_ws;
    unsigned short* featsb = (unsigned short*)w;
    unsigned short* w1pqT  = (unsigned short*)(w + (1u << 20));
    float*          HS     = (float*)w;
    unsigned short* w1cT   = (unsigned short*)(w + (4u << 20));
    unsigned short* w2T    = (unsigned short*)(w + (4u << 20) + (128u << 10));
    float* P = (float*)(w + (5u << 20) + (128u << 10));
    float* Q = (float*)(w + (9u << 20) + (128u << 10));
    char* ints = w + (13u << 20) + (128u << 10);
    int*      counts  = (int*)ints;
    int*      csr_obj = (int*)(ints + 4096);
    unsigned* brec    = (unsigned*)(ints + 4096 + 131072);
    int*      bcnt    = (int*)(ints + 4096 + 131072 + 16384);
    int*      rank    = (int*)(ints + 4096 + 131072 + 16384 + 64);

    k_zero<<<1, 256, 0, stream>>>(counts);

    k_a<<<2112, 256, 0, stream>>>(W1, W2, feats, pairs, w1pqT, w1cT, w2T, featsb,
                                  out_pairs, counts, rank);
    k_b<<<641, 256, 0, stream>>>(counts, rank, pairs, csr_obj, brec, bcnt,
                                 featsb, w1pqT, b1, P, Q);

    k_zero_hs<<<256, 256, 0, stream>>>((float4*)HS);

    k_seg<<<8192, 256, 0, stream>>>(csr_obj, brec, bcnt, bb, w1cT, P, Q, HS);
    k_out<<<128, 256, 0, stream>>>(HS, w2T, feats, b2, counts, out_feats);

    k_copy<<<8192, 256, 0, stream>>>((const float4*)bb, (float4*)out_bb);
}

// Round 13
// 235.075 us; speedup vs baseline: 1.2585x; 1.0579x over previous
//
#include <hip/hip_runtime.h>

#define N_OBJ 1024
#define E_P   32768

typedef float f32x4 __attribute__((ext_vector_type(4)));
typedef short bf16x8 __attribute__((ext_vector_type(8)));
typedef unsigned short u16x4 __attribute__((ext_vector_type(4)));

__device__ __forceinline__ unsigned short f2bf(float f) {
    unsigned u = __float_as_uint(f);
    u = u + 0x7FFFu + ((u >> 16) & 1u);   // RNE
    return (unsigned short)(u >> 16);
}

// ---- copy split (f32x4 units): total = 1024*1024*64/4 = 16777216 ----
#define OFF_A    0
#define LEN_A    3670016
#define OFF_B    (OFF_A + LEN_A)
#define LEN_B    3145728
#define OFF_SEG  (OFF_B + LEN_B)
#define LEN_SEG  6815744
#define OFF_OUT  (OFF_SEG + LEN_SEG)
#define LEN_OUT  3145728

// Non-temporal copy: does NOT evict L2/L3 working set (Q/P/w1cT/bbg)
__device__ __forceinline__ void copy_nt(const f32x4* __restrict__ src,
                                        f32x4* __restrict__ dst,
                                        int off, int len, int nb, int cb) {
    int stride = nb * 256;
    int i = off + cb * 256 + threadIdx.x;
    int end = off + len;
    for (; i + stride < end; i += 2 * stride) {
        f32x4 a = __builtin_nontemporal_load(&src[i]);
        f32x4 b = __builtin_nontemporal_load(&src[i + stride]);
        __builtin_nontemporal_store(a, &dst[i]);
        __builtin_nontemporal_store(b, &dst[i + stride]);
    }
    if (i < end) {
        f32x4 a = __builtin_nontemporal_load(&src[i]);
        __builtin_nontemporal_store(a, &dst[i]);
    }
}

// ================= k_zero kernels =================
__global__ __launch_bounds__(256) void k_zero(int* __restrict__ counts) {
    ((int4*)counts)[threadIdx.x] = make_int4(0, 0, 0, 0);
}

__global__ __launch_bounds__(256) void k_zero_hs(float4* __restrict__ hs4) {
    int i = blockIdx.x * 256 + threadIdx.x;
    const int stride = 256 * 256;
    float4 z = make_float4(0.f, 0.f, 0.f, 0.f);
    #pragma unroll
    for (int it = 0; it < 4; ++it) { hs4[i] = z; i += stride; }
}

// ================= k_a: transposes + featsb + pairs/hist/rank + bbg gather + nt-copy =================
// grid 3552: bid%3==2 -> copy (1184); else job = (bid/3)*2 + bid%3 (0..2367)
__global__ __launch_bounds__(256) void k_a(const float* __restrict__ W1,
                                           const float* __restrict__ W2,
                                           const float* __restrict__ feats,
                                           const int* __restrict__ pairs,
                                           const float* __restrict__ bb,
                                           unsigned short* __restrict__ w1pqT,
                                           unsigned short* __restrict__ w1cT,
                                           unsigned short* __restrict__ w2T,
                                           unsigned short* __restrict__ featsb,
                                           float* __restrict__ out_pairs,
                                           int* __restrict__ counts,
                                           int* __restrict__ rank,
                                           float* __restrict__ bbg,
                                           const f32x4* __restrict__ csrc,
                                           f32x4* __restrict__ cdst) {
    int bid = blockIdx.x, tid = threadIdx.x;
    if ((bid % 3) == 2) { copy_nt(csrc, cdst, OFF_A, LEN_A, 1184, bid / 3); return; }
    int job = (bid / 3) * 2 + (bid % 3);
    if (job >= 2240) return;           // idle tail
    if (job >= 2112) {                 // bbg gather: bbg[e] = bb[sub_e*1024+obj_e]
        int e = (job - 2112) * 256 + tid;
        int sub = pairs[2 * e], obj = pairs[2 * e + 1];
        const f32x4* src = (const f32x4*)&bb[((size_t)sub * 1024 + (size_t)obj) * 64];
        f32x4* dst = (f32x4*)&bbg[(size_t)e * 64];
        #pragma unroll
        for (int i = 0; i < 16; ++i) {
            f32x4 v = __builtin_nontemporal_load(&src[i]);
            dst[i] = v;
        }
        return;
    }
    if (job >= 1856) {                 // pairs passthrough + histogram + rank
        int i = (job - 1856) * 256 + tid;
        out_pairs[i] = (float)pairs[i];
        if (i < E_P) rank[i] = atomicAdd(&counts[pairs[2 * i]], 1);
        return;
    }
    if (job >= 1600) {                 // featsb straight convert
        int base = (job - 1600) * 2048 + tid * 8;
        float4 v0 = *(const float4*)&feats[base];
        float4 v1 = *(const float4*)&feats[base + 4];
        u16x4 o0 = { f2bf(v0.x), f2bf(v0.y), f2bf(v0.z), f2bf(v0.w) };
        u16x4 o1 = { f2bf(v1.x), f2bf(v1.y), f2bf(v1.z), f2bf(v1.w) };
        *(u16x4*)&featsb[base] = o0;
        *(u16x4*)&featsb[base + 4] = o1;
        return;
    }
    const float* in; unsigned short* out;
    int LDI, LDO, r0, c0, nbase, kbase;
    if (job < 1024) {                  // W1[0:1024] -> w1pqT [2048][512]
        r0 = (job >> 5) * 32; c0 = (job & 31) * 32;
        in = W1; LDI = 1024; out = w1pqT; LDO = 512;
        nbase = c0 + (r0 >= 512 ? 1024 : 0); kbase = r0 & 511;
    } else if (job < 1088) {           // W1[1024:1088] -> w1cT [1024][64]
        int t = job - 1024; r0 = 1024 + (t >> 5) * 32; c0 = (t & 31) * 32;
        in = W1; LDI = 1024; out = w1cT; LDO = 64;
        nbase = c0; kbase = r0 - 1024;
    } else {                           // W2 [1024][512] -> w2T [512][1024]
        int t = job - 1088; r0 = (t >> 4) * 32; c0 = (t & 15) * 32;
        in = W2; LDI = 512; out = w2T; LDO = 1024;
        nbase = c0; kbase = r0;
    }
    __shared__ float lds[32][33];
    int ti = tid >> 3, tj = (tid & 7) * 4;
    float4 v = *(const float4*)&in[(size_t)(r0 + ti) * LDI + c0 + tj];
    lds[ti][tj] = v.x; lds[ti][tj + 1] = v.y; lds[ti][tj + 2] = v.z; lds[ti][tj + 3] = v.w;
    __syncthreads();
    int oc = tid >> 3, oj = (tid & 7) * 4;
    u16x4 o = { f2bf(lds[oj][oc]), f2bf(lds[oj + 1][oc]),
                f2bf(lds[oj + 2][oc]), f2bf(lds[oj + 3][oc]) };
    *(u16x4*)&out[(size_t)(nbase + oc) * LDO + kbase + oj] = o;
}

// ================= k_b: brec-build + scatter(csr_obj,csr_e) + PQ GEMM + nt-copy =================
// grid 1923: bid%3<2 -> copy (1282); bid%3==2 -> role = bid/3 (0..640)
__global__ __launch_bounds__(256) void k_b(const int* __restrict__ counts,
                                           const int* __restrict__ rank,
                                           const int* __restrict__ pairs,
                                           int* __restrict__ csr_obj,
                                           int* __restrict__ csr_e,
                                           unsigned* __restrict__ brec,
                                           int* __restrict__ bcnt,
                                           const unsigned short* __restrict__ featsb,
                                           const unsigned short* __restrict__ w1pqT,
                                           const float* __restrict__ b1,
                                           float* __restrict__ P, float* __restrict__ Q,
                                           const f32x4* __restrict__ csrc,
                                           f32x4* __restrict__ cdst) {
    int bid = blockIdx.x, tid = threadIdx.x;
    if ((bid % 3) < 2) { copy_nt(csrc, cdst, OFF_B, LEN_B, 1282, (bid / 3) * 2 + (bid % 3)); return; }
    int role = bid / 3;

    if (role >= 129) {                 // ---- PQ GEMM tile ----
        int job = role - 129;
        int m0 = (job >> 5) * 64, n0 = (job & 31) * 64;
        int w = tid >> 6, l = tid & 63;
        int ln = l & 15, kb = (l >> 4) * 8;
        int row = m0 + w * 16 + ln;
        f32x4 acc[4] = {};
        for (int k0 = 0; k0 < 512; k0 += 32) {
            bf16x8 a = *(const bf16x8*)&featsb[(size_t)row * 512 + k0 + kb];
            #pragma unroll
            for (int f = 0; f < 4; ++f) {
                bf16x8 b = *(const bf16x8*)&w1pqT[(size_t)(n0 + f * 16 + ln) * 512 + k0 + kb];
                acc[f] = __builtin_amdgcn_mfma_f32_16x16x32_bf16(a, b, acc[f], 0, 0, 0);
            }
        }
        int mr = m0 + w * 16 + (l >> 4) * 4;
        if (n0 < 1024) {
            #pragma unroll
            for (int f = 0; f < 4; ++f) {
                int n = n0 + f * 16 + ln;
                float b1v = b1[n];
                #pragma unroll
                for (int r = 0; r < 4; ++r)
                    P[(size_t)(mr + r) * 1024 + n] = acc[f][r] + b1v;
            }
        } else {
            #pragma unroll
            for (int f = 0; f < 4; ++f) {
                int n = n0 - 1024 + f * 16 + ln;
                #pragma unroll
                for (int r = 0; r < 4; ++r)
                    Q[(size_t)(mr + r) * 1024 + n] = acc[f][r];
            }
        }
        return;
    }

    // ---- roles 0..128: redundant exclusive scan of counts in LDS ----
    __shared__ int sbuf[2][256];
    __shared__ int soff[1024];
    int c[4]; int s = 0;
    #pragma unroll
    for (int i = 0; i < 4; ++i) { c[i] = counts[tid * 4 + i]; s += c[i]; }
    sbuf[0][tid] = s;
    __syncthreads();
    int sel = 0;
    for (int d = 1; d < 256; d <<= 1) {
        int v = sbuf[sel][tid];
        if (tid >= d) v += sbuf[sel][tid - d];
        sbuf[sel ^ 1][tid] = v;
        sel ^= 1;
        __syncthreads();
    }
    int base = sbuf[sel][tid] - s;
    int run = base;
    #pragma unroll
    for (int i = 0; i < 4; ++i) { soff[tid * 4 + i] = run; run += c[i]; }
    __syncthreads();

    if (role >= 1) {                   // ---- scatter (no atomics) ----
        int e = (role - 1) * 256 + tid;
        int sub = pairs[2 * e];
        int pos = soff[sub] + rank[e];
        csr_obj[pos] = pairs[2 * e + 1];
        csr_e[pos] = e;
        return;
    }

    // ---- role 0: batch-32 records ----
    int nb[4]; int t = 0;
    #pragma unroll
    for (int i = 0; i < 4; ++i) { nb[i] = (c[i] + 31) >> 5; t += nb[i]; }
    __syncthreads();
    sbuf[0][tid] = t;
    __syncthreads();
    sel = 0;
    for (int d = 1; d < 256; d <<= 1) {
        int v = sbuf[sel][tid];
        if (tid >= d) v += sbuf[sel][tid - d];
        sbuf[sel ^ 1][tid] = v;
        sel ^= 1;
        __syncthreads();
    }
    int bpos = sbuf[sel][tid] - t;
    int run2 = base;
    #pragma unroll
    for (int i = 0; i < 4; ++i) {
        int seg = tid * 4 + i;
        for (int k = 0; k < nb[i]; ++k) {
            int st = run2 + k * 32;
            int cnt = c[i] - k * 32; if (cnt > 32) cnt = 32;
            brec[bpos++] = (unsigned)st | ((unsigned)seg << 16) | ((unsigned)(cnt - 1) << 26);
        }
        run2 += c[i];
    }
    if (tid == 255) bcnt[0] = bpos;
}

// ================= k_seg: quarter-blocks + LDS-staged Q + bbg (L2) + nt-copy =================
// grid 10240: bid%5==4 -> copy (2048); else job = (bid/5)*4 + bid%5 (0..8191)
__global__ __launch_bounds__(256) void k_seg(const int* __restrict__ csr_obj,
                                             const int* __restrict__ csr_e,
                                             const unsigned* __restrict__ brec,
                                             const int* __restrict__ bcnt,
                                             const float* __restrict__ bbg,
                                             const unsigned short* __restrict__ w1cT,
                                             const float* __restrict__ P,
                                             const float* __restrict__ Q,
                                             float* __restrict__ HS,
                                             const f32x4* __restrict__ csrc,
                                             f32x4* __restrict__ cdst) {
    int bid = blockIdx.x;
    if ((bid % 5) == 4) { copy_nt(csrc, cdst, OFF_SEG, LEN_SEG, 2048, bid / 5); return; }
    int job = (bid / 5) * 4 + (bid % 5);
    int b = job >> 2, qd = job & 3;
    if (b >= bcnt[0]) return;
    unsigned rec = brec[b];
    const int start = rec & 0xFFFF;
    const int seg = (rec >> 16) & 0x3FF;
    const int n = ((rec >> 26) & 31) + 1;

    const int tid = threadIdx.x, w = tid >> 6, l = tid & 63;
    const int ln = l & 15, g4 = l >> 4, kb = g4 * 8;
    const int cbase = qd * 256;
    const int wbase = cbase + w * 64;

    __shared__ float qs[32][256];

    {
        int p = tid >> 3, j = tid & 7;
        int op = csr_obj[start + (p < n ? p : n - 1)];
        const float* qrow = &Q[(size_t)op * 1024 + cbase];
        #pragma unroll
        for (int i = 0; i < 8; ++i) {
            int c = j * 4 + i * 32;
            *(float4*)&qs[p][c] = *(const float4*)&qrow[c];
        }
    }

    const int nA = n < 16 ? n : 16;
    const int nB = n - 16;
    int iA = start + (ln < nA ? ln : nA - 1);
    int iB = (nB > 0) ? (start + 16 + (ln < nB ? ln : nB - 1)) : iA;
    int eA = csr_e[iA];
    int eB = csr_e[iB];

    const float* brA = &bbg[(size_t)eA * 64];
    const float* brB = &bbg[(size_t)eB * 64];
    float4 a0 = *(const float4*)&brA[kb];
    float4 a1 = *(const float4*)&brA[kb + 4];
    float4 a2 = *(const float4*)&brA[32 + kb];
    float4 a3 = *(const float4*)&brA[32 + kb + 4];
    float4 c0 = *(const float4*)&brB[kb];
    float4 c1 = *(const float4*)&brB[kb + 4];
    float4 c2 = *(const float4*)&brB[32 + kb];
    float4 c3 = *(const float4*)&brB[32 + kb + 4];
    bf16x8 A0a, A1a, A0b, A1b;
    A0a[0] = (short)f2bf(a0.x); A0a[1] = (short)f2bf(a0.y); A0a[2] = (short)f2bf(a0.z); A0a[3] = (short)f2bf(a0.w);
    A0a[4] = (short)f2bf(a1.x); A0a[5] = (short)f2bf(a1.y); A0a[6] = (short)f2bf(a1.z); A0a[7] = (short)f2bf(a1.w);
    A1a[0] = (short)f2bf(a2.x); A1a[1] = (short)f2bf(a2.y); A1a[2] = (short)f2bf(a2.z); A1a[3] = (short)f2bf(a2.w);
    A1a[4] = (short)f2bf(a3.x); A1a[5] = (short)f2bf(a3.y); A1a[6] = (short)f2bf(a3.z); A1a[7] = (short)f2bf(a3.w);
    A0b[0] = (short)f2bf(c0.x); A0b[1] = (short)f2bf(c0.y); A0b[2] = (short)f2bf(c0.z); A0b[3] = (short)f2bf(c0.w);
    A0b[4] = (short)f2bf(c1.x); A0b[5] = (short)f2bf(c1.y); A0b[6] = (short)f2bf(c1.z); A0b[7] = (short)f2bf(c1.w);
    A1b[0] = (short)f2bf(c2.x); A1b[1] = (short)f2bf(c2.y); A1b[2] = (short)f2bf(c2.z); A1b[3] = (short)f2bf(c2.w);
    A1b[4] = (short)f2bf(c3.x); A1b[5] = (short)f2bf(c3.y); A1b[6] = (short)f2bf(c3.z); A1b[7] = (short)f2bf(c3.w);

    bool vA0 = (g4 * 4 + 0) < nA, vA1 = (g4 * 4 + 1) < nA;
    bool vA2 = (g4 * 4 + 2) < nA, vA3 = (g4 * 4 + 3) < nA;
    bool vB0 = (g4 * 4 + 0) < nB, vB1 = (g4 * 4 + 1) < nB;
    bool vB2 = (g4 * 4 + 2) < nB, vB3 = (g4 * 4 + 3) < nB;

    float pv[4];
    #pragma unroll
    for (int f = 0; f < 4; ++f)
        pv[f] = P[(size_t)seg * 1024 + wbase + f * 16 + ln];

    __syncthreads();

    #pragma unroll
    for (int f = 0; f < 4; ++f) {
        int col = wbase + f * 16 + ln;
        int cc = col - cbase;
        const unsigned short* wr = &w1cT[(size_t)col * 64];
        bf16x8 b0 = *(const bf16x8*)&wr[kb];
        bf16x8 b1 = *(const bf16x8*)&wr[32 + kb];
        f32x4 dA = {0.f, 0.f, 0.f, 0.f};
        dA = __builtin_amdgcn_mfma_f32_16x16x32_bf16(A0a, b0, dA, 0, 0, 0);
        dA = __builtin_amdgcn_mfma_f32_16x16x32_bf16(A1a, b1, dA, 0, 0, 0);
        f32x4 dB = {0.f, 0.f, 0.f, 0.f};
        dB = __builtin_amdgcn_mfma_f32_16x16x32_bf16(A0b, b0, dB, 0, 0, 0);
        dB = __builtin_amdgcn_mfma_f32_16x16x32_bf16(A1b, b1, dB, 0, 0, 0);
        float qA0 = qs[g4 * 4 + 0][cc];
        float qA1 = qs[g4 * 4 + 1][cc];
        float qA2 = qs[g4 * 4 + 2][cc];
        float qA3 = qs[g4 * 4 + 3][cc];
        float qB0 = qs[16 + g4 * 4 + 0][cc];
        float qB1 = qs[16 + g4 * 4 + 1][cc];
        float qB2 = qs[16 + g4 * 4 + 2][cc];
        float qB3 = qs[16 + g4 * 4 + 3][cc];
        float h = 0.f;
        h += vA0 ? fmaxf(dA[0] + pv[f] + qA0, 0.f) : 0.f;
        h += vA1 ? fmaxf(dA[1] + pv[f] + qA1, 0.f) : 0.f;
        h += vA2 ? fmaxf(dA[2] + pv[f] + qA2, 0.f) : 0.f;
        h += vA3 ? fmaxf(dA[3] + pv[f] + qA3, 0.f) : 0.f;
        h += vB0 ? fmaxf(dB[0] + pv[f] + qB0, 0.f) : 0.f;
        h += vB1 ? fmaxf(dB[1] + pv[f] + qB1, 0.f) : 0.f;
        h += vB2 ? fmaxf(dB[2] + pv[f] + qB2, 0.f) : 0.f;
        h += vB3 ? fmaxf(dB[3] + pv[f] + qB3, 0.f) : 0.f;
        h += __shfl_xor(h, 16);
        h += __shfl_xor(h, 32);
        if (l < 16) atomicAdd(&HS[(size_t)seg * 1024 + wbase + f * 16 + l], h);
    }
}

// ================= k_out: (feats + HS@W2 + cnt*b2)/(1+cnt) + nt-copy =================
// grid 2176: bid%17==16 -> gemm (128); else copy (2048)
__global__ __launch_bounds__(256) void k_out(const float* __restrict__ HS,
                                             const unsigned short* __restrict__ w2T,
                                             const float* __restrict__ feats,
                                             const float* __restrict__ b2,
                                             const int* __restrict__ counts,
                                             float* __restrict__ out0,
                                             const f32x4* __restrict__ csrc,
                                             f32x4* __restrict__ cdst) {
    int bid = blockIdx.x;
    if ((bid % 17) != 16) { copy_nt(csrc, cdst, OFF_OUT, LEN_OUT, 2048, (bid / 17) * 16 + (bid % 17)); return; }
    int job = bid / 17;
    int m0 = (job >> 3) * 64, n0 = (job & 7) * 64;
    int tid = threadIdx.x, w = tid >> 6, l = tid & 63;
    int ln = l & 15, kb = (l >> 4) * 8;
    int row = m0 + w * 16 + ln;
    f32x4 acc[4] = {};
    for (int k0 = 0; k0 < 1024; k0 += 32) {
        const float* hp = &HS[(size_t)row * 1024 + k0 + kb];
        float4 h0 = *(const float4*)&hp[0];
        float4 h1 = *(const float4*)&hp[4];
        bf16x8 a;
        a[0] = (short)f2bf(h0.x); a[1] = (short)f2bf(h0.y); a[2] = (short)f2bf(h0.z); a[3] = (short)f2bf(h0.w);
        a[4] = (short)f2bf(h1.x); a[5] = (short)f2bf(h1.y); a[6] = (short)f2bf(h1.z); a[7] = (short)f2bf(h1.w);
        #pragma unroll
        for (int f = 0; f < 4; ++f) {
            bf16x8 b = *(const bf16x8*)&w2T[(size_t)(n0 + f * 16 + ln) * 1024 + k0 + kb];
            acc[f] = __builtin_amdgcn_mfma_f32_16x16x32_bf16(a, b, acc[f], 0, 0, 0);
        }
    }
    int mr = m0 + w * 16 + (l >> 4) * 4;
    float cv[4], inv[4];
    #pragma unroll
    for (int r = 0; r < 4; ++r) {
        float c = (float)counts[mr + r];
        cv[r] = c;
        inv[r] = 1.0f / (1.0f + c);
    }
    #pragma unroll
    for (int f = 0; f < 4; ++f) {
        int n = n0 + f * 16 + ln;
        float b2v = b2[n];
        #pragma unroll
        for (int r = 0; r < 4; ++r) {
            float fv = feats[(size_t)(mr + r) * 512 + n];
            out0[(size_t)(mr + r) * 512 + n] = (fv + acc[f][r] + cv[r] * b2v) * inv[r];
        }
    }
}

extern "C" void kernel_launch(void* const* d_in, const int* in_sizes, int n_in,
                              void* d_out, int out_size, void* d_ws, size_t ws_size,
                              hipStream_t stream) {
    const float* feats = (const float*)d_in[0];
    const float* bb    = (const float*)d_in[1];
    const int*   pairs = (const int*)d_in[2];
    const float* W1    = (const float*)d_in[3];
    const float* b1    = (const float*)d_in[4];
    const float* W2    = (const float*)d_in[5];
    const float* b2    = (const float*)d_in[6];

    float* out        = (float*)d_out;
    float* out_feats  = out;
    float* out_bb     = out + (size_t)N_OBJ * 512;
    float* out_pairs  = out + (size_t)N_OBJ * 512 + (size_t)N_OBJ * N_OBJ * 64;

    // ---- workspace layout (~23 MB) ----
    char* w = (char*)d_ws;
    unsigned short* featsb = (unsigned short*)w;                 // [0,1M)
    unsigned short* w1pqT  = (unsigned short*)(w + (1u << 20));  // [1M,3M)
    float*          HS     = (float*)w;                          // [0,4M) aliases featsb/w1pqT
    unsigned short* w1cT   = (unsigned short*)(w + (4u << 20));
    unsigned short* w2T    = (unsigned short*)(w + (4u << 20) + (128u << 10));
    float* P = (float*)(w + (5u << 20) + (128u << 10));
    float* Q = (float*)(w + (9u << 20) + (128u << 10));
    char* ints = w + (13u << 20) + (128u << 10);
    int*      counts  = (int*)ints;
    int*      csr_obj = (int*)(ints + 4096);
    unsigned* brec    = (unsigned*)(ints + 4096 + 131072);
    int*      bcnt    = (int*)(ints + 4096 + 131072 + 16384);
    int*      rank    = (int*)(ints + 4096 + 131072 + 16384 + 64);
    int*      csr_e   = (int*)(ints + 4096 + 131072 + 16384 + 64 + 131072);
    float*    bbg     = (float*)(w + (14u << 20));               // 8 MB, [14M,22M)

    const f32x4* cbb  = (const f32x4*)bb;
    f32x4*       cobb = (f32x4*)out_bb;

    k_zero<<<1, 256, 0, stream>>>(counts);

    k_a<<<3552, 256, 0, stream>>>(W1, W2, feats, pairs, bb, w1pqT, w1cT, w2T, featsb,
                                  out_pairs, counts, rank, bbg, cbb, cobb);
    k_b<<<1923, 256, 0, stream>>>(counts, rank, pairs, csr_obj, csr_e, brec, bcnt,
                                  featsb, w1pqT, b1, P, Q, cbb, cobb);

    k_zero_hs<<<256, 256, 0, stream>>>((float4*)HS);

    k_seg<<<10240, 256, 0, stream>>>(csr_obj, csr_e, brec, bcnt, bbg, w1cT, P, Q, HS,
                                     cbb, cobb);
    k_out<<<2176, 256, 0, stream>>>(HS, w2T, feats, b2, counts, out_feats, cbb, cobb);
}

// Round 14
// 218.619 us; speedup vs baseline: 1.3532x; 1.0753x over previous
//
#include <hip/hip_runtime.h>

#define N_OBJ 1024
#define E_P   32768

typedef float f32x4 __attribute__((ext_vector_type(4)));
typedef short bf16x8 __attribute__((ext_vector_type(8)));
typedef unsigned short u16x4 __attribute__((ext_vector_type(4)));

__device__ __forceinline__ unsigned short f2bf(float f) {
    unsigned u = __float_as_uint(f);
    u = u + 0x7FFFu + ((u >> 16) & 1u);   // RNE
    return (unsigned short)(u >> 16);
}
__device__ __forceinline__ float bf2f(unsigned short u) {
    return __uint_as_float(((unsigned)u) << 16);
}

// ---- copy split (f32x4 units): total = 1024*1024*64/4 = 16777216 ----
#define OFF_A    0
#define LEN_A    5242880
#define OFF_B    (OFF_A + LEN_A)
#define LEN_B    4194304
#define OFF_SEG  (OFF_B + LEN_B)
#define LEN_SEG  4194304
#define OFF_OUT  (OFF_SEG + LEN_SEG)
#define LEN_OUT  3145728

__device__ __forceinline__ void copy_nt(const f32x4* __restrict__ src,
                                        f32x4* __restrict__ dst,
                                        int off, int len, int nb, int cb) {
    int stride = nb * 256;
    int i = off + cb * 256 + threadIdx.x;
    int end = off + len;
    for (; i + stride < end; i += 2 * stride) {
        f32x4 a = __builtin_nontemporal_load(&src[i]);
        f32x4 b = __builtin_nontemporal_load(&src[i + stride]);
        __builtin_nontemporal_store(a, &dst[i]);
        __builtin_nontemporal_store(b, &dst[i + stride]);
    }
    if (i < end) {
        f32x4 a = __builtin_nontemporal_load(&src[i]);
        __builtin_nontemporal_store(a, &dst[i]);
    }
}

__global__ __launch_bounds__(256) void k_zero(int* __restrict__ counts) {
    ((int4*)counts)[threadIdx.x] = make_int4(0, 0, 0, 0);
}

// ================= k_a: transposes + featsb + pairs/hist/rank + bbg(bf16) + HS-zero + nt-copy =================
// grid 3456: bid%3==2 -> copy (1152); else job = (bid/3)*2 + bid%3 (0..2303)
__global__ __launch_bounds__(256) void k_a(const float* __restrict__ W1,
                                           const float* __restrict__ W2,
                                           const float* __restrict__ feats,
                                           const int* __restrict__ pairs,
                                           const float* __restrict__ bb,
                                           unsigned short* __restrict__ w1pqT,
                                           unsigned short* __restrict__ w1cT,
                                           unsigned short* __restrict__ w2T,
                                           unsigned short* __restrict__ featsb,
                                           float* __restrict__ out_pairs,
                                           int* __restrict__ counts,
                                           int* __restrict__ rank,
                                           unsigned short* __restrict__ bbgb,
                                           f32x4* __restrict__ hs4,
                                           const f32x4* __restrict__ csrc,
                                           f32x4* __restrict__ cdst) {
    int bid = blockIdx.x, tid = threadIdx.x;
    if ((bid % 3) == 2) { copy_nt(csrc, cdst, OFF_A, LEN_A, 1152, bid / 3); return; }
    int job = (bid / 3) * 2 + (bid % 3);
    if (job >= 2240) {                 // HS zero: 64 blocks x 4096 f32x4
        int blk = job - 2240;
        f32x4 z = {0.f, 0.f, 0.f, 0.f};
        f32x4* p = hs4 + (size_t)blk * 4096 + tid;
        #pragma unroll
        for (int it = 0; it < 16; ++it) p[it * 256] = z;
        return;
    }
    if (job >= 2112) {                 // bbg gather -> bf16: bbgb[e] = bf16(bb[sub,obj])
        int e = (job - 2112) * 256 + tid;
        int sub = pairs[2 * e], obj = pairs[2 * e + 1];
        const f32x4* src = (const f32x4*)&bb[((size_t)sub * 1024 + (size_t)obj) * 64];
        u16x4* dst = (u16x4*)&bbgb[(size_t)e * 64];
        #pragma unroll
        for (int i = 0; i < 16; ++i) {
            f32x4 v = __builtin_nontemporal_load(&src[i]);
            u16x4 o = { f2bf(v.x), f2bf(v.y), f2bf(v.z), f2bf(v.w) };
            dst[i] = o;
        }
        return;
    }
    if (job >= 1856) {                 // pairs passthrough + histogram + rank
        int i = (job - 1856) * 256 + tid;
        out_pairs[i] = (float)pairs[i];
        if (i < E_P) rank[i] = atomicAdd(&counts[pairs[2 * i]], 1);
        return;
    }
    if (job >= 1600) {                 // featsb straight convert
        int base = (job - 1600) * 2048 + tid * 8;
        float4 v0 = *(const float4*)&feats[base];
        float4 v1 = *(const float4*)&feats[base + 4];
        u16x4 o0 = { f2bf(v0.x), f2bf(v0.y), f2bf(v0.z), f2bf(v0.w) };
        u16x4 o1 = { f2bf(v1.x), f2bf(v1.y), f2bf(v1.z), f2bf(v1.w) };
        *(u16x4*)&featsb[base] = o0;
        *(u16x4*)&featsb[base + 4] = o1;
        return;
    }
    const float* in; unsigned short* out;
    int LDI, LDO, r0, c0, nbase, kbase;
    if (job < 1024) {                  // W1[0:1024] -> w1pqT [2048][512]
        r0 = (job >> 5) * 32; c0 = (job & 31) * 32;
        in = W1; LDI = 1024; out = w1pqT; LDO = 512;
        nbase = c0 + (r0 >= 512 ? 1024 : 0); kbase = r0 & 511;
    } else if (job < 1088) {           // W1[1024:1088] -> w1cT [1024][64]
        int t = job - 1024; r0 = 1024 + (t >> 5) * 32; c0 = (t & 31) * 32;
        in = W1; LDI = 1024; out = w1cT; LDO = 64;
        nbase = c0; kbase = r0 - 1024;
    } else {                           // W2 [1024][512] -> w2T [512][1024]
        int t = job - 1088; r0 = (t >> 4) * 32; c0 = (t & 15) * 32;
        in = W2; LDI = 512; out = w2T; LDO = 1024;
        nbase = c0; kbase = r0;
    }
    __shared__ float lds[32][33];
    int ti = tid >> 3, tj = (tid & 7) * 4;
    float4 v = *(const float4*)&in[(size_t)(r0 + ti) * LDI + c0 + tj];
    lds[ti][tj] = v.x; lds[ti][tj + 1] = v.y; lds[ti][tj + 2] = v.z; lds[ti][tj + 3] = v.w;
    __syncthreads();
    int oc = tid >> 3, oj = (tid & 7) * 4;
    u16x4 o = { f2bf(lds[oj][oc]), f2bf(lds[oj + 1][oc]),
                f2bf(lds[oj + 2][oc]), f2bf(lds[oj + 3][oc]) };
    *(u16x4*)&out[(size_t)(nbase + oc) * LDO + kbase + oj] = o;
}

// ================= k_b: brec-build + scatter + PQ GEMM (Q -> bf16) + nt-copy =================
// grid 1923: bid%3<2 -> copy (1282); bid%3==2 -> role = bid/3 (0..640)
__global__ __launch_bounds__(256) void k_b(const int* __restrict__ counts,
                                           const int* __restrict__ rank,
                                           const int* __restrict__ pairs,
                                           int* __restrict__ csr_obj,
                                           int* __restrict__ csr_e,
                                           unsigned* __restrict__ brec,
                                           int* __restrict__ bcnt,
                                           const unsigned short* __restrict__ featsb,
                                           const unsigned short* __restrict__ w1pqT,
                                           const float* __restrict__ b1,
                                           float* __restrict__ P,
                                           unsigned short* __restrict__ Qb,
                                           const f32x4* __restrict__ csrc,
                                           f32x4* __restrict__ cdst) {
    int bid = blockIdx.x, tid = threadIdx.x;
    if ((bid % 3) < 2) { copy_nt(csrc, cdst, OFF_B, LEN_B, 1282, (bid / 3) * 2 + (bid % 3)); return; }
    int role = bid / 3;

    if (role >= 129) {                 // ---- PQ GEMM tile ----
        int job = role - 129;
        int m0 = (job >> 5) * 64, n0 = (job & 31) * 64;
        int w = tid >> 6, l = tid & 63;
        int ln = l & 15, kb = (l >> 4) * 8;
        int row = m0 + w * 16 + ln;
        f32x4 acc[4] = {};
        for (int k0 = 0; k0 < 512; k0 += 32) {
            bf16x8 a = *(const bf16x8*)&featsb[(size_t)row * 512 + k0 + kb];
            #pragma unroll
            for (int f = 0; f < 4; ++f) {
                bf16x8 b = *(const bf16x8*)&w1pqT[(size_t)(n0 + f * 16 + ln) * 512 + k0 + kb];
                acc[f] = __builtin_amdgcn_mfma_f32_16x16x32_bf16(a, b, acc[f], 0, 0, 0);
            }
        }
        int mr = m0 + w * 16 + (l >> 4) * 4;
        if (n0 < 1024) {
            #pragma unroll
            for (int f = 0; f < 4; ++f) {
                int n = n0 + f * 16 + ln;
                float b1v = b1[n];
                #pragma unroll
                for (int r = 0; r < 4; ++r)
                    P[(size_t)(mr + r) * 1024 + n] = acc[f][r] + b1v;
            }
        } else {
            #pragma unroll
            for (int f = 0; f < 4; ++f) {
                int n = n0 - 1024 + f * 16 + ln;
                #pragma unroll
                for (int r = 0; r < 4; ++r)
                    Qb[(size_t)(mr + r) * 1024 + n] = f2bf(acc[f][r]);
            }
        }
        return;
    }

    // ---- roles 0..128: redundant exclusive scan of counts in LDS ----
    __shared__ int sbuf[2][256];
    __shared__ int soff[1024];
    int c[4]; int s = 0;
    #pragma unroll
    for (int i = 0; i < 4; ++i) { c[i] = counts[tid * 4 + i]; s += c[i]; }
    sbuf[0][tid] = s;
    __syncthreads();
    int sel = 0;
    for (int d = 1; d < 256; d <<= 1) {
        int v = sbuf[sel][tid];
        if (tid >= d) v += sbuf[sel][tid - d];
        sbuf[sel ^ 1][tid] = v;
        sel ^= 1;
        __syncthreads();
    }
    int base = sbuf[sel][tid] - s;
    int run = base;
    #pragma unroll
    for (int i = 0; i < 4; ++i) { soff[tid * 4 + i] = run; run += c[i]; }
    __syncthreads();

    if (role >= 1) {                   // ---- scatter (no atomics) ----
        int e = (role - 1) * 256 + tid;
        int sub = pairs[2 * e];
        int pos = soff[sub] + rank[e];
        csr_obj[pos] = pairs[2 * e + 1];
        csr_e[pos] = e;
        return;
    }

    // ---- role 0: batch-32 records ----
    int nb[4]; int t = 0;
    #pragma unroll
    for (int i = 0; i < 4; ++i) { nb[i] = (c[i] + 31) >> 5; t += nb[i]; }
    __syncthreads();
    sbuf[0][tid] = t;
    __syncthreads();
    sel = 0;
    for (int d = 1; d < 256; d <<= 1) {
        int v = sbuf[sel][tid];
        if (tid >= d) v += sbuf[sel][tid - d];
        sbuf[sel ^ 1][tid] = v;
        sel ^= 1;
        __syncthreads();
    }
    int bpos = sbuf[sel][tid] - t;
    int run2 = base;
    #pragma unroll
    for (int i = 0; i < 4; ++i) {
        int seg = tid * 4 + i;
        for (int k = 0; k < nb[i]; ++k) {
            int st = run2 + k * 32;
            int cnt = c[i] - k * 32; if (cnt > 32) cnt = 32;
            brec[bpos++] = (unsigned)st | ((unsigned)seg << 16) | ((unsigned)(cnt - 1) << 26);
        }
        run2 += c[i];
    }
    if (tid == 255) bcnt[0] = bpos;
}

// ================= k_seg: XCD-pinned quarters + bf16 Q/bbg + nt-copy =================
// grid 12288 = 8*1536. x=bid&7 -> XCD; k=bid>>3.
//   k<1024: compute, quarter qd=x>>1 (pinned to XCD pair), batch b = k*2+(x&1)
//   k>=1024: copy block cb=(k-1024)*8+x (4096 blocks)
__global__ __launch_bounds__(256) void k_seg(const int* __restrict__ csr_obj,
                                             const int* __restrict__ csr_e,
                                             const unsigned* __restrict__ brec,
                                             const int* __restrict__ bcnt,
                                             const unsigned short* __restrict__ bbgb,
                                             const unsigned short* __restrict__ w1cT,
                                             const float* __restrict__ P,
                                             const unsigned short* __restrict__ Qb,
                                             float* __restrict__ HS,
                                             const f32x4* __restrict__ csrc,
                                             f32x4* __restrict__ cdst) {
    int bid = blockIdx.x, tid = threadIdx.x;
    int x = bid & 7, k = bid >> 3;
    if (k >= 1024) { copy_nt(csrc, cdst, OFF_SEG, LEN_SEG, 4096, (k - 1024) * 8 + x); return; }
    int qd = x >> 1;
    int b = k * 2 + (x & 1);
    if (b >= bcnt[0]) return;
    unsigned rec = brec[b];
    const int start = rec & 0xFFFF;
    const int seg = (rec >> 16) & 0x3FF;
    const int n = ((rec >> 26) & 31) + 1;

    const int w = tid >> 6, l = tid & 63;
    const int ln = l & 15, g4 = l >> 4, kb = g4 * 8;
    const int cbase = qd * 256;
    const int wbase = cbase + w * 64;

    __shared__ unsigned short qs[32][264];   // bf16 Q quarter slices (~16.9 KB)

    // ---- stage Qb (bf16): thread t -> pair p=t>>3, 4x16B each; only if p<n ----
    {
        int p = tid >> 3, j = tid & 7;
        if (p < n) {
            int op = csr_obj[start + p];
            const uint4* qrow = (const uint4*)&Qb[(size_t)op * 1024 + cbase];
            #pragma unroll
            for (int i = 0; i < 4; ++i) {
                uint4 v = qrow[j * 4 + i];
                *(uint4*)&qs[p][(j * 4 + i) * 8] = v;
            }
        }
    }

    const int nA = n < 16 ? n : 16;
    const int nB = n - 16;
    int iA = start + (ln < nA ? ln : nA - 1);
    int iB = (nB > 0) ? (start + 16 + (ln < nB ? ln : nB - 1)) : iA;
    int eA = csr_e[iA];
    int eB = csr_e[iB];

    const unsigned short* brA = &bbgb[(size_t)eA * 64];
    const unsigned short* brB = &bbgb[(size_t)eB * 64];
    bf16x8 A0a = *(const bf16x8*)&brA[kb];
    bf16x8 A1a = *(const bf16x8*)&brA[32 + kb];
    bf16x8 A0b = *(const bf16x8*)&brB[kb];
    bf16x8 A1b = *(const bf16x8*)&brB[32 + kb];

    bool vA0 = (g4 * 4 + 0) < nA, vA1 = (g4 * 4 + 1) < nA;
    bool vA2 = (g4 * 4 + 2) < nA, vA3 = (g4 * 4 + 3) < nA;
    bool vB0 = (g4 * 4 + 0) < nB, vB1 = (g4 * 4 + 1) < nB;
    bool vB2 = (g4 * 4 + 2) < nB, vB3 = (g4 * 4 + 3) < nB;

    float pv[4];
    #pragma unroll
    for (int f = 0; f < 4; ++f)
        pv[f] = P[(size_t)seg * 1024 + wbase + f * 16 + ln];

    __syncthreads();

    #pragma unroll
    for (int f = 0; f < 4; ++f) {
        int col = wbase + f * 16 + ln;
        int cc = col - cbase;
        const unsigned short* wr = &w1cT[(size_t)col * 64];
        bf16x8 b0 = *(const bf16x8*)&wr[kb];
        bf16x8 b1 = *(const bf16x8*)&wr[32 + kb];
        f32x4 dA = {0.f, 0.f, 0.f, 0.f};
        dA = __builtin_amdgcn_mfma_f32_16x16x32_bf16(A0a, b0, dA, 0, 0, 0);
        dA = __builtin_amdgcn_mfma_f32_16x16x32_bf16(A1a, b1, dA, 0, 0, 0);
        f32x4 dB = {0.f, 0.f, 0.f, 0.f};
        dB = __builtin_amdgcn_mfma_f32_16x16x32_bf16(A0b, b0, dB, 0, 0, 0);
        dB = __builtin_amdgcn_mfma_f32_16x16x32_bf16(A1b, b1, dB, 0, 0, 0);
        float qA0 = bf2f(qs[g4 * 4 + 0][cc]);
        float qA1 = bf2f(qs[g4 * 4 + 1][cc]);
        float qA2 = bf2f(qs[g4 * 4 + 2][cc]);
        float qA3 = bf2f(qs[g4 * 4 + 3][cc]);
        float qB0 = bf2f(qs[16 + g4 * 4 + 0][cc]);
        float qB1 = bf2f(qs[16 + g4 * 4 + 1][cc]);
        float qB2 = bf2f(qs[16 + g4 * 4 + 2][cc]);
        float qB3 = bf2f(qs[16 + g4 * 4 + 3][cc]);
        float h = 0.f;
        h += vA0 ? fmaxf(dA[0] + pv[f] + qA0, 0.f) : 0.f;
        h += vA1 ? fmaxf(dA[1] + pv[f] + qA1, 0.f) : 0.f;
        h += vA2 ? fmaxf(dA[2] + pv[f] + qA2, 0.f) : 0.f;
        h += vA3 ? fmaxf(dA[3] + pv[f] + qA3, 0.f) : 0.f;
        h += vB0 ? fmaxf(dB[0] + pv[f] + qB0, 0.f) : 0.f;
        h += vB1 ? fmaxf(dB[1] + pv[f] + qB1, 0.f) : 0.f;
        h += vB2 ? fmaxf(dB[2] + pv[f] + qB2, 0.f) : 0.f;
        h += vB3 ? fmaxf(dB[3] + pv[f] + qB3, 0.f) : 0.f;
        h += __shfl_xor(h, 16);
        h += __shfl_xor(h, 32);
        if (l < 16) atomicAdd(&HS[(size_t)seg * 1024 + wbase + f * 16 + l], h);
    }
}

// ================= k_out: (feats + HS@W2 + cnt*b2)/(1+cnt) + nt-copy =================
// grid 2176: bid%17==16 -> gemm (128); else copy (2048)
__global__ __launch_bounds__(256) void k_out(const float* __restrict__ HS,
                                             const unsigned short* __restrict__ w2T,
                                             const float* __restrict__ feats,
                                             const float* __restrict__ b2,
                                             const int* __restrict__ counts,
                                             float* __restrict__ out0,
                                             const f32x4* __restrict__ csrc,
                                             f32x4* __restrict__ cdst) {
    int bid = blockIdx.x;
    if ((bid % 17) != 16) { copy_nt(csrc, cdst, OFF_OUT, LEN_OUT, 2048, (bid / 17) * 16 + (bid % 17)); return; }
    int job = bid / 17;
    int m0 = (job >> 3) * 64, n0 = (job & 7) * 64;
    int tid = threadIdx.x, w = tid >> 6, l = tid & 63;
    int ln = l & 15, kb = (l >> 4) * 8;
    int row = m0 + w * 16 + ln;
    f32x4 acc[4] = {};
    for (int k0 = 0; k0 < 1024; k0 += 32) {
        const float* hp = &HS[(size_t)row * 1024 + k0 + kb];
        float4 h0 = *(const float4*)&hp[0];
        float4 h1 = *(const float4*)&hp[4];
        bf16x8 a;
        a[0] = (short)f2bf(h0.x); a[1] = (short)f2bf(h0.y); a[2] = (short)f2bf(h0.z); a[3] = (short)f2bf(h0.w);
        a[4] = (short)f2bf(h1.x); a[5] = (short)f2bf(h1.y); a[6] = (short)f2bf(h1.z); a[7] = (short)f2bf(h1.w);
        #pragma unroll
        for (int f = 0; f < 4; ++f) {
            bf16x8 b = *(const bf16x8*)&w2T[(size_t)(n0 + f * 16 + ln) * 1024 + k0 + kb];
            acc[f] = __builtin_amdgcn_mfma_f32_16x16x32_bf16(a, b, acc[f], 0, 0, 0);
        }
    }
    int mr = m0 + w * 16 + (l >> 4) * 4;
    float cv[4], inv[4];
    #pragma unroll
    for (int r = 0; r < 4; ++r) {
        float c = (float)counts[mr + r];
        cv[r] = c;
        inv[r] = 1.0f / (1.0f + c);
    }
    #pragma unroll
    for (int f = 0; f < 4; ++f) {
        int n = n0 + f * 16 + ln;
        float b2v = b2[n];
        #pragma unroll
        for (int r = 0; r < 4; ++r) {
            float fv = feats[(size_t)(mr + r) * 512 + n];
            out0[(size_t)(mr + r) * 512 + n] = (fv + acc[f][r] + cv[r] * b2v) * inv[r];
        }
    }
}

extern "C" void kernel_launch(void* const* d_in, const int* in_sizes, int n_in,
                              void* d_out, int out_size, void* d_ws, size_t ws_size,
                              hipStream_t stream) {
    const float* feats = (const float*)d_in[0];
    const float* bb    = (const float*)d_in[1];
    const int*   pairs = (const int*)d_in[2];
    const float* W1    = (const float*)d_in[3];
    const float* b1    = (const float*)d_in[4];
    const float* W2    = (const float*)d_in[5];
    const float* b2    = (const float*)d_in[6];

    float* out        = (float*)d_out;
    float* out_feats  = out;
    float* out_bb     = out + (size_t)N_OBJ * 512;
    float* out_pairs  = out + (size_t)N_OBJ * 512 + (size_t)N_OBJ * N_OBJ * 64;

    // ---- workspace layout (~18.6 MB), HS NOT aliased ----
    char* w = (char*)d_ws;
    unsigned short* featsb = (unsigned short*)w;                              // [0,1M)
    unsigned short* w1pqT  = (unsigned short*)(w + (1u << 20));               // [1M,3M)
    unsigned short* w1cT   = (unsigned short*)(w + (3u << 20));               // 128K
    unsigned short* w2T    = (unsigned short*)(w + (3u << 20) + (128u << 10)); // 1M
    float*          HS     = (float*)(w + (4u << 20) + (128u << 10));         // 4M
    float*          P      = (float*)(w + (8u << 20) + (128u << 10));         // 4M
    unsigned short* Qb     = (unsigned short*)(w + (12u << 20) + (128u << 10)); // 2M
    unsigned short* bbgb   = (unsigned short*)(w + (14u << 20) + (128u << 10)); // 4M
    char* ints = w + (18u << 20) + (128u << 10);
    int*      counts  = (int*)ints;
    int*      csr_obj = (int*)(ints + 4096);
    int*      csr_e   = (int*)(ints + 4096 + 131072);
    unsigned* brec    = (unsigned*)(ints + 4096 + 262144);
    int*      bcnt    = (int*)(ints + 4096 + 262144 + 16384);
    int*      rank    = (int*)(ints + 4096 + 262144 + 16384 + 64);

    const f32x4* cbb  = (const f32x4*)bb;
    f32x4*       cobb = (f32x4*)out_bb;

    k_zero<<<1, 256, 0, stream>>>(counts);

    k_a<<<3456, 256, 0, stream>>>(W1, W2, feats, pairs, bb, w1pqT, w1cT, w2T, featsb,
                                  out_pairs, counts, rank, bbgb, (f32x4*)HS, cbb, cobb);
    k_b<<<1923, 256, 0, stream>>>(counts, rank, pairs, csr_obj, csr_e, brec, bcnt,
                                  featsb, w1pqT, b1, P, Qb, cbb, cobb);
    k_seg<<<12288, 256, 0, stream>>>(csr_obj, csr_e, brec, bcnt, bbgb, w1cT, P, Qb, HS,
                                     cbb, cobb);
    k_out<<<2176, 256, 0, stream>>>(HS, w2T, feats, b2, counts, out_feats, cbb, cobb);
}